// Round 1
// baseline (180.054 us; speedup 1.0000x reference)
//
#include <hip/hip_runtime.h>

#define CIN 3
#define HH 512
#define WW 512
#define COUT 64
#define KF 48          // 3*4*4
#define HO 128
#define WO 128

// ---------------------------------------------------------------------------
// Kernel 1: top singular value of W (64x48) via G = W^T W, 3 squarings (G^8),
// 64 power iterations, Rayleigh quotient with original G.  Single wave.
// ---------------------------------------------------------------------------
__global__ __launch_bounds__(64) void prep_sigma(const float* __restrict__ w,
                                                 float* __restrict__ sigma_out) {
  __shared__ float sW[COUT * KF];   // 12 KB
  __shared__ float sG[KF * KF];     // 9.2 KB
  __shared__ float sM[KF * KF];     // 9.2 KB
  __shared__ float sv[64];
  const int t = threadIdx.x;
  const int row = (t < KF) ? t : (KF - 1);

  // load W (3072 floats) as float4
  {
    const float4* w4 = (const float4*)w;
    float4* s4 = (float4*)sW;
#pragma unroll
    for (int q = 0; q < 12; ++q) s4[q * 64 + t] = w4[q * 64 + t];
  }
  __syncthreads();

  // G row `row`:  h[j] = sum_m W[m][row] * W[m][j]
  float h[KF];
#pragma unroll
  for (int j = 0; j < KF; ++j) h[j] = 0.f;
#pragma unroll 1
  for (int m = 0; m < COUT; ++m) {
    const float wmi = sW[m * KF + row];
    const float4* wr = (const float4*)(sW + m * KF);
#pragma unroll
    for (int q = 0; q < 12; ++q) {
      float4 g = wr[q];
      h[4*q+0] = fmaf(wmi, g.x, h[4*q+0]);
      h[4*q+1] = fmaf(wmi, g.y, h[4*q+1]);
      h[4*q+2] = fmaf(wmi, g.z, h[4*q+2]);
      h[4*q+3] = fmaf(wmi, g.w, h[4*q+3]);
    }
  }
  __syncthreads();
  if (t < KF) {
    float4* gr = (float4*)(sG + row * KF);
#pragma unroll
    for (int q = 0; q < 12; ++q)
      gr[q] = make_float4(h[4*q+0], h[4*q+1], h[4*q+2], h[4*q+3]);
  }
  __syncthreads();

  float r[KF];
#pragma unroll
  for (int j = 0; j < KF; ++j) r[j] = h[j];

  // 3 squarings: G -> G^2 -> G^4 -> G^8 (symmetric: H[i][j] = dot(row_i,row_j))
#pragma unroll 1
  for (int s = 0; s < 3; ++s) {
    const float* src = (s == 0) ? sG : sM;
#pragma unroll
    for (int j = 0; j < KF; ++j) {
      const float4* rj = (const float4*)(src + j * KF);
      float a0 = 0.f, a1 = 0.f, a2 = 0.f, a3 = 0.f;
#pragma unroll
      for (int q = 0; q < 12; ++q) {
        float4 g = rj[q];
        a0 = fmaf(r[4*q+0], g.x, a0);
        a1 = fmaf(r[4*q+1], g.y, a1);
        a2 = fmaf(r[4*q+2], g.z, a2);
        a3 = fmaf(r[4*q+3], g.w, a3);
      }
      h[j] = (a0 + a1) + (a2 + a3);
    }
    __syncthreads();             // everyone done reading src
    if (t < KF) {
      float4* mr = (float4*)(sM + row * KF);
#pragma unroll
      for (int q = 0; q < 12; ++q)
        mr[q] = make_float4(h[4*q+0], h[4*q+1], h[4*q+2], h[4*q+3]);
    }
#pragma unroll
    for (int j = 0; j < KF; ++j) r[j] = h[j];
    __syncthreads();
  }

  // 64 power iterations with M = G^8 (rows in r) -> effective exponent 512
  float v = (t < KF) ? 1.f : 0.f;
#pragma unroll 1
  for (int it = 0; it < 64; ++it) {
    sv[t] = v;
    __syncthreads();
    const float4* vv = (const float4*)sv;
    float a0 = 0.f, a1 = 0.f, a2 = 0.f, a3 = 0.f;
#pragma unroll
    for (int q = 0; q < 12; ++q) {
      float4 g = vv[q];
      a0 = fmaf(r[4*q+0], g.x, a0);
      a1 = fmaf(r[4*q+1], g.y, a1);
      a2 = fmaf(r[4*q+2], g.z, a2);
      a3 = fmaf(r[4*q+3], g.w, a3);
    }
    float nv = (t < KF) ? ((a0 + a1) + (a2 + a3)) : 0.f;
    float ss = nv * nv;
#pragma unroll
    for (int m = 32; m >= 1; m >>= 1) ss += __shfl_xor(ss, m, 64);
    v = nv * rsqrtf(ss);
    __syncthreads();
  }

  // Rayleigh quotient with ORIGINAL G: lambda = (v^T G v)/(v^T v)
  sv[t] = v;
  __syncthreads();
  {
    const float4* vv = (const float4*)sv;
    const float4* gr = (const float4*)(sG + row * KF);
    float a0 = 0.f, a1 = 0.f, a2 = 0.f, a3 = 0.f;
#pragma unroll
    for (int q = 0; q < 12; ++q) {
      float4 g = gr[q];
      float4 u = vv[q];
      a0 = fmaf(g.x, u.x, a0);
      a1 = fmaf(g.y, u.y, a1);
      a2 = fmaf(g.z, u.z, a2);
      a3 = fmaf(g.w, u.w, a3);
    }
    float gv = (t < KF) ? ((a0 + a1) + (a2 + a3)) : 0.f;
    float num = gv * v;
    float den = v * v;
#pragma unroll
    for (int m = 32; m >= 1; m >>= 1) {
      num += __shfl_xor(num, m, 64);
      den += __shfl_xor(den, m, 64);
    }
    if (t == 0) sigma_out[0] = sqrtf(num / den);
  }
}

// ---------------------------------------------------------------------------
// Kernel 2: fused strided conv (4x4, stride 4) + bias + 8-center soft-VQ.
// One thread per output spatial position (b,i,j); loops over 64 channels.
// ---------------------------------------------------------------------------
__global__ __launch_bounds__(256) void conv_vq(
    const float* __restrict__ x, const float* __restrict__ w,
    const float* __restrict__ bias, const float* __restrict__ centers,
    const float* __restrict__ sigma_ptr, float* __restrict__ out) {
  __shared__ float swt[COUT * KF];  // normalized weights, 12 KB
  __shared__ float sb[COUT];
  __shared__ float sc[8];
  const int t = threadIdx.x;

  const float inv_sigma = 1.0f / sigma_ptr[0];
  for (int k = t; k < COUT * KF; k += 256) swt[k] = w[k] * inv_sigma;
  if (t < COUT) sb[t] = bias[t];
  if (t < 8) sc[t] = centers[t];
  __syncthreads();

  const int pos = blockIdx.x * 256 + t;      // 16*128*128 = 262144 total
  const int b   = pos >> 14;
  const int rem = pos & 16383;
  const int i   = rem >> 7;
  const int j   = rem & 127;

  // load 3x4x4 input patch as 12 float4 (coalesced: lane j -> 16B stride)
  const float* xp = x + (size_t)b * (CIN * HH * WW) + (size_t)(4 * i) * WW + 4 * j;
  float p[KF];
#pragma unroll
  for (int ci = 0; ci < CIN; ++ci) {
#pragma unroll
    for (int kh = 0; kh < 4; ++kh) {
      float4 v4 = *(const float4*)(xp + (size_t)ci * (HH * WW) + kh * WW);
      p[(ci * 4 + kh) * 4 + 0] = v4.x;
      p[(ci * 4 + kh) * 4 + 1] = v4.y;
      p[(ci * 4 + kh) * 4 + 2] = v4.z;
      p[(ci * 4 + kh) * 4 + 3] = v4.w;
    }
  }

  const float c0 = sc[0], c1 = sc[1], c2 = sc[2], c3 = sc[3],
              c4 = sc[4], c5 = sc[5], c6 = sc[6], c7 = sc[7];

  float* op = out + (size_t)b * (COUT * HO * WO) + rem;

#pragma unroll 4
  for (int c = 0; c < COUT; ++c) {
    const float4* wr = (const float4*)(swt + c * KF);
    float a0 = 0.f, a1 = 0.f, a2 = 0.f, a3 = 0.f;
#pragma unroll
    for (int q = 0; q < 12; ++q) {
      float4 g = wr[q];
      a0 = fmaf(p[4*q+0], g.x, a0);
      a1 = fmaf(p[4*q+1], g.y, a1);
      a2 = fmaf(p[4*q+2], g.z, a2);
      a3 = fmaf(p[4*q+3], g.w, a3);
    }
    const float y = (a0 + a1) + (a2 + a3) + sb[c];

    // soft VQ: softmax(-(y-c_k)^2) weighted sum of centers (max-stabilized)
    float t0 = y - c0, t1 = y - c1, t2 = y - c2, t3 = y - c3;
    float t4 = y - c4, t5 = y - c5, t6 = y - c6, t7 = y - c7;
    float d0 = t0*t0, d1 = t1*t1, d2 = t2*t2, d3 = t3*t3;
    float d4 = t4*t4, d5 = t5*t5, d6 = t6*t6, d7 = t7*t7;
    float dmin = fminf(fminf(fminf(d0, d1), fminf(d2, d3)),
                       fminf(fminf(d4, d5), fminf(d6, d7)));
    float e0 = __expf(dmin - d0), e1 = __expf(dmin - d1);
    float e2 = __expf(dmin - d2), e3 = __expf(dmin - d3);
    float e4 = __expf(dmin - d4), e5 = __expf(dmin - d5);
    float e6 = __expf(dmin - d6), e7 = __expf(dmin - d7);
    float den = ((e0 + e1) + (e2 + e3)) + ((e4 + e5) + (e6 + e7));
    float num = ((fmaf(c0, e0, c1 * e1)) + (fmaf(c2, e2, c3 * e3))) +
                ((fmaf(c4, e4, c5 * e5)) + (fmaf(c6, e6, c7 * e7)));
    op[(size_t)c * (HO * WO)] = __fdividef(num, den);
  }
}

extern "C" void kernel_launch(void* const* d_in, const int* in_sizes, int n_in,
                              void* d_out, int out_size, void* d_ws, size_t ws_size,
                              hipStream_t stream) {
  const float* x       = (const float*)d_in[0];
  const float* w       = (const float*)d_in[1];
  const float* b       = (const float*)d_in[2];
  const float* centers = (const float*)d_in[3];
  float* out   = (float*)d_out;
  float* sigma = (float*)d_ws;   // 4 bytes of scratch

  prep_sigma<<<1, 64, 0, stream>>>(w, sigma);
  conv_vq<<<(16 * HO * WO) / 256, 256, 0, stream>>>(x, w, b, centers, sigma, out);
}

// Round 2
// 78.992 us; speedup vs baseline: 2.2794x; 2.2794x over previous
//
#include <hip/hip_runtime.h>

#define CIN 3
#define HH 512
#define WW 512
#define COUT 64
#define KF 48          // 3*4*4
#define HO 128
#define WO 128
#define LDA 52         // padded row stride for 48x48 matrices (bank-conflict-free)

// ---------------------------------------------------------------------------
// Kernel 1: top singular value of W (64x48).  256 threads, one block.
//   G = W^T W  (48x48, 3x3-tile per thread)
//   5 squarings  -> M = G^32   (ping-pong LDS buffers, LDA=52 padding)
//   12 matvecs with M  -> v ~ G^384 v0  (normalized each step)
//   Rayleigh quotient with ORIGINAL G  -> lambda, sigma = sqrt(lambda)
// ---------------------------------------------------------------------------
__global__ __launch_bounds__(256) void prep_sigma(const float* __restrict__ w,
                                                  float* __restrict__ sigma_out) {
  __shared__ float sW[COUT * KF];   // 12 KB
  __shared__ float sG[KF * LDA];    // original G (kept for Rayleigh)
  __shared__ float sA[KF * LDA];
  __shared__ float sB[KF * LDA];
  __shared__ float sv[64];
  __shared__ float sp[256];
  const int t = threadIdx.x;

  // ---- load W ----
  {
    const float4* w4 = (const float4*)w;
    float4* s4 = (float4*)sW;
#pragma unroll
    for (int q = 0; q < 3; ++q) s4[q * 256 + t] = w4[q * 256 + t];
  }
  __syncthreads();

  // ---- G = W^T W, 3x3 tile per thread (16x16 tiles cover 48x48) ----
  const int ti = t >> 4, tj = t & 15;
  const int i0 = 3 * ti, j0 = 3 * tj;
  {
    float acc[3][3] = {{0.f}};
#pragma unroll 4
    for (int m = 0; m < COUT; ++m) {
      const float* wr = sW + m * KF;
      float a0 = wr[i0], a1 = wr[i0 + 1], a2 = wr[i0 + 2];
      float b0 = wr[j0], b1 = wr[j0 + 1], b2 = wr[j0 + 2];
      acc[0][0] = fmaf(a0, b0, acc[0][0]);
      acc[0][1] = fmaf(a0, b1, acc[0][1]);
      acc[0][2] = fmaf(a0, b2, acc[0][2]);
      acc[1][0] = fmaf(a1, b0, acc[1][0]);
      acc[1][1] = fmaf(a1, b1, acc[1][1]);
      acc[1][2] = fmaf(a1, b2, acc[1][2]);
      acc[2][0] = fmaf(a2, b0, acc[2][0]);
      acc[2][1] = fmaf(a2, b1, acc[2][1]);
      acc[2][2] = fmaf(a2, b2, acc[2][2]);
    }
#pragma unroll
    for (int ii = 0; ii < 3; ++ii)
#pragma unroll
      for (int jj = 0; jj < 3; ++jj) {
        sG[(i0 + ii) * LDA + j0 + jj] = acc[ii][jj];
        sA[(i0 + ii) * LDA + j0 + jj] = acc[ii][jj];
      }
  }
  __syncthreads();

  // ---- 5 squarings: sA -> sB -> sA -> sB -> sA -> sB  (M ends in sB) ----
#pragma unroll 1
  for (int s = 0; s < 5; ++s) {
    const float* src = (s & 1) ? sB : sA;
    float* dst = (s & 1) ? sA : sB;
    float acc[3][3] = {{0.f}};
#pragma unroll
    for (int q = 0; q < 12; ++q) {
      float4 ar0 = *(const float4*)(src + (i0 + 0) * LDA + 4 * q);
      float4 ar1 = *(const float4*)(src + (i0 + 1) * LDA + 4 * q);
      float4 ar2 = *(const float4*)(src + (i0 + 2) * LDA + 4 * q);
      float4 br0 = *(const float4*)(src + (j0 + 0) * LDA + 4 * q);
      float4 br1 = *(const float4*)(src + (j0 + 1) * LDA + 4 * q);
      float4 br2 = *(const float4*)(src + (j0 + 2) * LDA + 4 * q);
#define DOT4(A, B, C) \
      C = fmaf(A.x, B.x, C); C = fmaf(A.y, B.y, C); \
      C = fmaf(A.z, B.z, C); C = fmaf(A.w, B.w, C);
      DOT4(ar0, br0, acc[0][0]); DOT4(ar0, br1, acc[0][1]); DOT4(ar0, br2, acc[0][2]);
      DOT4(ar1, br0, acc[1][0]); DOT4(ar1, br1, acc[1][1]); DOT4(ar1, br2, acc[1][2]);
      DOT4(ar2, br0, acc[2][0]); DOT4(ar2, br1, acc[2][1]); DOT4(ar2, br2, acc[2][2]);
#undef DOT4
    }
#pragma unroll
    for (int ii = 0; ii < 3; ++ii)
#pragma unroll
      for (int jj = 0; jj < 3; ++jj)
        dst[(i0 + ii) * LDA + j0 + jj] = acc[ii][jj];
    __syncthreads();   // writes visible before next squaring reads dst
  }

  // ---- init v ----
  if (t < 64) sv[t] = (t < KF) ? 1.0f : 0.f;
  __syncthreads();

  // ---- 12 matvecs with M = sB (row = t>>2, seg = t&3; 12 floats per seg) ----
#pragma unroll 1
  for (int it = 0; it < 12; ++it) {
    float partial = 0.f;
    if (t < 192) {
      const int row = t >> 2, seg = t & 3;
      const float* mr = sB + row * LDA + seg * 12;
      const float4* v4 = (const float4*)sv;
#pragma unroll
      for (int q = 0; q < 3; ++q) {
        float4 m4 = *(const float4*)(mr + 4 * q);
        float4 vv = v4[seg * 3 + q];
        partial = fmaf(m4.x, vv.x, partial);
        partial = fmaf(m4.y, vv.y, partial);
        partial = fmaf(m4.z, vv.z, partial);
        partial = fmaf(m4.w, vv.w, partial);
      }
    }
    sp[t] = partial;
    __syncthreads();
    if (t < 64) {
      float nv = 0.f;
      if (t < KF) nv = (sp[4 * t] + sp[4 * t + 1]) + (sp[4 * t + 2] + sp[4 * t + 3]);
      float ss = nv * nv;
#pragma unroll
      for (int m = 32; m >= 1; m >>= 1) ss += __shfl_xor(ss, m, 64);
      sv[t] = (t < KF) ? nv * rsqrtf(ss) : 0.f;
    }
    __syncthreads();
  }

  // ---- Rayleigh with original G:  lambda = (v^T G v) / (v^T v) ----
  {
    float partial = 0.f;
    if (t < 192) {
      const int row = t >> 2, seg = t & 3;
      const float* mr = sG + row * LDA + seg * 12;
      const float4* v4 = (const float4*)sv;
#pragma unroll
      for (int q = 0; q < 3; ++q) {
        float4 m4 = *(const float4*)(mr + 4 * q);
        float4 vv = v4[seg * 3 + q];
        partial = fmaf(m4.x, vv.x, partial);
        partial = fmaf(m4.y, vv.y, partial);
        partial = fmaf(m4.z, vv.z, partial);
        partial = fmaf(m4.w, vv.w, partial);
      }
    }
    sp[t] = partial;
    __syncthreads();
    if (t < 64) {
      float nv = 0.f;
      if (t < KF) nv = (sp[4 * t] + sp[4 * t + 1]) + (sp[4 * t + 2] + sp[4 * t + 3]);
      float vt = sv[t];
      float num = nv * vt;
      float den = vt * vt;
#pragma unroll
      for (int m = 32; m >= 1; m >>= 1) {
        num += __shfl_xor(num, m, 64);
        den += __shfl_xor(den, m, 64);
      }
      if (t == 0) sigma_out[0] = sqrtf(num / den);
    }
  }
}

// ---------------------------------------------------------------------------
// Kernel 2: fused strided conv (4x4, stride 4) + bias + 8-center soft-VQ.
// ZERO LDS: weights/bias/centers read at wave-uniform addresses -> scalar
// loads (constant cache), FMA uses the SGPR operand slot.  Accumulate with
// RAW weights, scale by 1/sigma at the end.
// soft-VQ:  softmax(-(y-c)^2) propto exp(2*y*c - c^2)   (e^{-y^2} cancels)
// ---------------------------------------------------------------------------
__global__ __launch_bounds__(256) void conv_vq(
    const float* __restrict__ x, const float* __restrict__ w,
    const float* __restrict__ bias, const float* __restrict__ centers,
    const float* __restrict__ sigma_ptr, float* __restrict__ out) {
  const int t = threadIdx.x;
  const int pos = blockIdx.x * 256 + t;      // 16*128*128 = 262144 total
  const int b   = pos >> 14;
  const int rem = pos & 16383;
  const int i   = rem >> 7;
  const int j   = rem & 127;

  const float inv_sigma = 1.0f / sigma_ptr[0];

  float cc[8], tc[8], mc2[8];
#pragma unroll
  for (int k = 0; k < 8; ++k) {
    float c = centers[k];          // uniform -> scalar load
    cc[k] = c; tc[k] = 2.0f * c; mc2[k] = -c * c;
  }

  // load 3x4x4 input patch as 12 float4 (coalesced: lane j -> 16B stride)
  const float* xp = x + (size_t)b * (CIN * HH * WW) + (size_t)(4 * i) * WW + 4 * j;
  float p[KF];
#pragma unroll
  for (int ci = 0; ci < CIN; ++ci) {
#pragma unroll
    for (int kh = 0; kh < 4; ++kh) {
      float4 v4 = *(const float4*)(xp + (size_t)ci * (HH * WW) + kh * WW);
      p[(ci * 4 + kh) * 4 + 0] = v4.x;
      p[(ci * 4 + kh) * 4 + 1] = v4.y;
      p[(ci * 4 + kh) * 4 + 2] = v4.z;
      p[(ci * 4 + kh) * 4 + 3] = v4.w;
    }
  }

  float* op = out + (size_t)b * (COUT * HO * WO) + rem;

#pragma unroll 2
  for (int c = 0; c < COUT; ++c) {
    const float4* wr = (const float4*)(w + c * KF);   // uniform -> s_load
    float a0 = 0.f, a1 = 0.f, a2 = 0.f, a3 = 0.f;
#pragma unroll
    for (int q = 0; q < 12; ++q) {
      float4 g = wr[q];
      a0 = fmaf(p[4*q+0], g.x, a0);
      a1 = fmaf(p[4*q+1], g.y, a1);
      a2 = fmaf(p[4*q+2], g.z, a2);
      a3 = fmaf(p[4*q+3], g.w, a3);
    }
    const float y = fmaf((a0 + a1) + (a2 + a3), inv_sigma, bias[c]);

    float e0 = __expf(fmaf(tc[0], y, mc2[0]));
    float e1 = __expf(fmaf(tc[1], y, mc2[1]));
    float e2 = __expf(fmaf(tc[2], y, mc2[2]));
    float e3 = __expf(fmaf(tc[3], y, mc2[3]));
    float e4 = __expf(fmaf(tc[4], y, mc2[4]));
    float e5 = __expf(fmaf(tc[5], y, mc2[5]));
    float e6 = __expf(fmaf(tc[6], y, mc2[6]));
    float e7 = __expf(fmaf(tc[7], y, mc2[7]));
    float den = ((e0 + e1) + (e2 + e3)) + ((e4 + e5) + (e6 + e7));
    float num = (fmaf(cc[0], e0, cc[1] * e1) + fmaf(cc[2], e2, cc[3] * e3)) +
                (fmaf(cc[4], e4, cc[5] * e5) + fmaf(cc[6], e6, cc[7] * e7));
    op[(size_t)c * (HO * WO)] = __fdividef(num, den);
  }
}

extern "C" void kernel_launch(void* const* d_in, const int* in_sizes, int n_in,
                              void* d_out, int out_size, void* d_ws, size_t ws_size,
                              hipStream_t stream) {
  const float* x       = (const float*)d_in[0];
  const float* w       = (const float*)d_in[1];
  const float* b       = (const float*)d_in[2];
  const float* centers = (const float*)d_in[3];
  float* out   = (float*)d_out;
  float* sigma = (float*)d_ws;   // 4 bytes of scratch

  prep_sigma<<<1, 256, 0, stream>>>(w, sigma);
  conv_vq<<<(16 * HO * WO) / 256, 256, 0, stream>>>(x, w, b, centers, sigma, out);
}